// Round 6
// baseline (1783.370 us; speedup 1.0000x reference)
//
#include <hip/hip_runtime.h>
#include <math.h>

#define S_TOT 2048
#define B_    64
#define E_    256
#define H_    256

typedef __fp16 half2v __attribute__((ext_vector_type(2)));

// Fused kernel: blocks [0, scan_blocks) run the sequential scan (one block per
// batch, 512 threads); blocks [scan_blocks, grid) run the xp GEMM for the NEXT
// chunk (first 256 threads). Kernel boundary = producer->consumer sync.
__global__ __launch_bounds__(512, 1) void fused_step(
    const float* __restrict__ A,       // sentence chunk for gemm [Mc, E] (or null)
    const float* __restrict__ Wih,     // [E, H]
    const float* __restrict__ bias,    // [H]
    float*       __restrict__ xp_next, // [chunk*B, H] gemm output
    const float* __restrict__ xp_cur,  // [steps, B, H] scan input
    const float* __restrict__ Whh,     // [H, H]
    float*       __restrict__ h,       // [B, H] persistent state (= d_out)
    int steps, int scan_blocks)
{
    __shared__ float smem[32 * 68 + 32 * 64];   // gemm tiles; scan reuses front
    const int tid = threadIdx.x;

    if ((int)blockIdx.x < scan_blocks) {
        // ------------- scan: h_new = tanh(xp + h @ Whh), 512 threads ---------
        // thread (jg = tid>>4, ks = tid&15): outputs j0..j0+7 (j0 = jg*8),
        // k-range [ks*16, ks*16+16).  W slice as 64 half2 VGPRs; per-step dot
        // via v_dot2_f32_f16 (f16 products exact in fp32, fp32 accumulate).
        half2v* hb = (half2v*)smem;      // ping-pong [2][128] half2 (h pairs)
        const int b  = blockIdx.x;
        const int ks = tid & 15;
        const int jg = tid >> 4;         // 0..31
        const int j0 = jg << 3;
        // output index this lane holds after the split-butterfly reduction
        const int jf = j0 + ((ks & 1) << 2) + (ks & 2) + ((ks >> 2) & 1);

        // w[kp][jj] = (Whh[ks*16+2kp][j0+jj], Whh[ks*16+2kp+1][j0+jj]) as f16x2
        half2v w[8][8];
        #pragma unroll
        for (int kp = 0; kp < 8; kp++) {
            const float* r0 = &Whh[(size_t)(ks * 16 + 2 * kp) * H_ + j0];
            const float* r1 = r0 + H_;
            #pragma unroll
            for (int jj = 0; jj < 8; jj++) {
                half2v v = __builtin_amdgcn_cvt_pkrtz(r0[jj], r1[jj]);
                int vi = __builtin_bit_cast(int, v);
                asm volatile("" : "+v"(vi));     // defeat load-sinking
                w[kp][jj] = __builtin_bit_cast(half2v, vi);
            }
        }

        if (tid < 128)
            hb[tid] = __builtin_amdgcn_cvt_pkrtz(h[b * H_ + 2 * tid],
                                                 h[b * H_ + 2 * tid + 1]);
        float xpn = 0.f;
        if (ks < 8) xpn = xp_cur[(size_t)b * H_ + jf];
        __syncthreads();

        int p = 0;
        for (int s = 0; s < steps; s++) {
            const float xpc = xpn;
            if (ks < 8 && s + 1 < steps)
                xpn = xp_cur[((size_t)(s + 1) * B_ + b) * H_ + jf];

            // this lane's 16-value h segment: 2 x ds_read_b128 (8 half2)
            half2v hk[8];
            {
                const float4* hs = (const float4*)&hb[p * 128 + ks * 8];
                float4 t0 = hs[0], t1 = hs[1];
                *(float4*)&hk[0] = t0;
                *(float4*)&hk[4] = t1;
            }

            float acc[8] = {0.f, 0.f, 0.f, 0.f, 0.f, 0.f, 0.f, 0.f};
            #pragma unroll
            for (int kp = 0; kp < 8; kp++) {
                #pragma unroll
                for (int jj = 0; jj < 8; jj++)
                    acc[jj] = __builtin_amdgcn_fdot2(hk[kp], w[kp][jj],
                                                     acc[jj], false);
            }

            // split-butterfly reduce across the 16 ks lanes (xor1/2/4 split,
            // xor8 plain add); each lane ends with ONE output (index jf).
            const bool b0 = (ks & 1), b1 = (ks & 2), b2 = (ks & 4);
            float r0, r1, r2, r3, q0, q1, v;
            {
                float s0 = b0 ? acc[0] : acc[4];
                float s1 = b0 ? acc[1] : acc[5];
                float s2 = b0 ? acc[2] : acc[6];
                float s3 = b0 ? acc[3] : acc[7];
                r0 = (b0 ? acc[4] : acc[0]) + __shfl_xor(s0, 1);
                r1 = (b0 ? acc[5] : acc[1]) + __shfl_xor(s1, 1);
                r2 = (b0 ? acc[6] : acc[2]) + __shfl_xor(s2, 1);
                r3 = (b0 ? acc[7] : acc[3]) + __shfl_xor(s3, 1);
            }
            {
                float s0 = b1 ? r0 : r2;
                float s1 = b1 ? r1 : r3;
                q0 = (b1 ? r2 : r0) + __shfl_xor(s0, 2);
                q1 = (b1 ? r3 : r1) + __shfl_xor(s1, 2);
            }
            {
                float s0 = b2 ? q0 : q1;
                v = (b2 ? q1 : q0) + __shfl_xor(s0, 4);
            }
            v += __shfl_xor(v, 8);       // fold the two 8-lane halves

            v += xpc;
            const float e2 = __expf(2.f * v);
            const float hn = 1.f - 2.f / (e2 + 1.f);   // tanh(v)
            if (ks < 8) {
                ((__fp16*)hb)[(p ^ 1) * 256 + jf] = (__fp16)hn;
                if (s == steps - 1) h[b * H_ + jf] = hn;   // fp32 carry-out
            }
            __syncthreads();
            p ^= 1;
        }
    } else if (A != nullptr && tid < 256) {
        // ---------------- gemm: xp_next = A @ Wih + bias (256 threads) -------
        float (*As)[68] = (float(*)[68])smem;
        float (*Bs)[64] = (float(*)[64])(smem + 32 * 68);

        const int gid = blockIdx.x - scan_blocks;
        const int bm = (gid >> 2) * 64;
        const int bn = (gid & 3) * 64;
        const int tx = tid & 15;
        const int ty = tid >> 4;

        float acc[4][4] = {};

        const int ar = tid >> 3;
        const int ak = (tid & 7) << 2;
        const int br = tid >> 4;
        const int bc = (tid & 15) << 2;

        for (int k0 = 0; k0 < E_; k0 += 32) {
            float4 a0 = *(const float4*)&A[(size_t)(bm + ar)      * E_ + k0 + ak];
            float4 a1 = *(const float4*)&A[(size_t)(bm + ar + 32) * E_ + k0 + ak];
            float4 bv0 = *(const float4*)&Wih[(size_t)(k0 + br)      * H_ + bn + bc];
            float4 bv1 = *(const float4*)&Wih[(size_t)(k0 + br + 16) * H_ + bn + bc];

            As[ak+0][ar]    = a0.x; As[ak+1][ar]    = a0.y; As[ak+2][ar]    = a0.z; As[ak+3][ar]    = a0.w;
            As[ak+0][ar+32] = a1.x; As[ak+1][ar+32] = a1.y; As[ak+2][ar+32] = a1.z; As[ak+3][ar+32] = a1.w;
            *(float4*)&Bs[br][bc]      = bv0;
            *(float4*)&Bs[br + 16][bc] = bv1;
            __syncthreads();

            #pragma unroll
            for (int kk = 0; kk < 32; kk++) {
                const float4 av = *(const float4*)&As[kk][ty << 2];
                const float4 bv = *(const float4*)&Bs[kk][tx << 2];
                acc[0][0] += av.x*bv.x; acc[0][1] += av.x*bv.y; acc[0][2] += av.x*bv.z; acc[0][3] += av.x*bv.w;
                acc[1][0] += av.y*bv.x; acc[1][1] += av.y*bv.y; acc[1][2] += av.y*bv.z; acc[1][3] += av.y*bv.w;
                acc[2][0] += av.z*bv.x; acc[2][1] += av.z*bv.y; acc[2][2] += av.z*bv.z; acc[2][3] += av.z*bv.w;
                acc[3][0] += av.w*bv.x; acc[3][1] += av.w*bv.y; acc[3][2] += av.w*bv.z; acc[3][3] += av.w*bv.w;
            }
            __syncthreads();
        }

        const float4 bb = *(const float4*)&bias[bn + (tx << 2)];
        #pragma unroll
        for (int i = 0; i < 4; i++) {
            float4 o;
            o.x = acc[i][0] + bb.x;
            o.y = acc[i][1] + bb.y;
            o.z = acc[i][2] + bb.z;
            o.w = acc[i][3] + bb.w;
            *(float4*)&xp_next[(size_t)(bm + (ty << 2) + i) * H_ + bn + (tx << 2)] = o;
        }
    }
}

extern "C" void kernel_launch(void* const* d_in, const int* in_sizes, int n_in,
                              void* d_out, int out_size, void* d_ws, size_t ws_size,
                              hipStream_t stream)
{
    const float* sentence = (const float*)d_in[0];  // [S,B,E]
    const float* h0       = (const float*)d_in[1];  // [B,H]
    const float* W_ih     = (const float*)d_in[2];  // [E,H]
    const float* W_hh     = (const float*)d_in[3];  // [H,H]
    const float* bias     = (const float*)d_in[4];  // [H]
    float* h  = (float*)d_out;
    float* ws = (float*)d_ws;

    // two ping-pong xp buffers, each [chunk*B, H]
    int chunk = 256;
    while ((size_t)2 * chunk * B_ * H_ * sizeof(float) > ws_size && chunk > 32)
        chunk >>= 1;
    const int nchunk = S_TOT / chunk;
    float* buf[2] = { ws, ws + (size_t)chunk * B_ * H_ };

    hipMemcpyAsync(h, h0, B_ * H_ * sizeof(float), hipMemcpyDeviceToDevice, stream);

    // pure gemm for chunk 0
    fused_step<<<chunk * 4, 512, 0, stream>>>(sentence, W_ih, bias, buf[0],
                                              nullptr, W_hh, h, 0, 0);
    for (int c = 0; c < nchunk; c++) {
        const bool last = (c == nchunk - 1);
        const int gemmb = last ? 0 : chunk * 4;
        const float* Anext = last ? nullptr
                                  : sentence + (size_t)(c + 1) * chunk * B_ * E_;
        fused_step<<<64 + gemmb, 512, 0, stream>>>(Anext, W_ih, bias,
                                                   buf[(c + 1) & 1],
                                                   buf[c & 1], W_hh, h,
                                                   chunk, 64);
    }
}

// Round 7
// 1439.927 us; speedup vs baseline: 1.2385x; 1.2385x over previous
//
#include <hip/hip_runtime.h>
#include <math.h>

#define S_TOT 2048
#define B_    64
#define E_    256
#define H_    256

typedef __fp16 half2v __attribute__((ext_vector_type(2)));

// Fused kernel: blocks [0, scan_blocks) run the sequential scan (one block per
// batch, 256 threads); blocks [scan_blocks, grid) run the xp GEMM for the NEXT
// chunk. Kernel boundary = producer->consumer sync between chunks.
//
// launch_bounds (256,1): 4 waves = exactly 1 wave/EU -> feasible bound, VGPR
// budget 512. R2 empirically kept 148 live VGPRs in this config; we need ~170.
__global__ __launch_bounds__(256, 1) void fused_step(
    const float* __restrict__ A,       // sentence chunk for gemm [Mc, E] (or null)
    const float* __restrict__ Wih,     // [E, H]
    const float* __restrict__ bias,    // [H]
    float*       __restrict__ xp_next, // [chunk*B, H] gemm output
    const float* __restrict__ xp_cur,  // [steps, B, H] scan input
    const float* __restrict__ Whh,     // [H, H]
    float*       __restrict__ h,       // [B, H] persistent state (= d_out)
    int steps, int scan_blocks)
{
    __shared__ float smem[32 * 68 + 32 * 64];   // gemm tiles; scan reuses front
    const int tid = threadIdx.x;

    if ((int)blockIdx.x < scan_blocks) {
        // ------------- scan: h_new = tanh(xp + h @ Whh), 256 threads ---------
        // thread (jg = tid>>3, ks = tid&7): outputs j0..j0+7 (j0 = jg*8),
        // k-range [ks*32, ks*32+32).  W slice = 128 half2 VGPRs; dot via
        // v_dot2_f32_f16 (f16 products exact in fp32, fp32 accumulate).
        // h ping-pong in LDS: 8 segments of 32 f16, stride 20 dwords ->
        // ks*20 mod 32 = {0,20,8,28,16,4,24,12}: conflict-free + 16B-aligned.
        float* hbuf = smem;              // [2][8][20] dwords
        const int b  = blockIdx.x;
        const int ks = tid & 7;
        const int jg = tid >> 3;         // 0..31
        const int j0 = jg << 3;
        // output index this lane holds after the split-butterfly reduction
        const int jf = j0 + ((ks & 1) << 2) + (ks & 2) + ((ks >> 2) & 1);

        // w[i][jj] = (Whh[ks*32+2i][j0+jj], Whh[ks*32+2i+1][j0+jj]) as f16x2
        half2v w[16][8];
        #pragma unroll
        for (int i = 0; i < 16; i++) {
            const float* r0 = &Whh[(size_t)(ks * 32 + 2 * i) * H_ + j0];
            const float* r1 = r0 + H_;
            #pragma unroll
            for (int jj = 0; jj < 8; jj++) {
                half2v v = __builtin_amdgcn_cvt_pkrtz(r0[jj], r1[jj]);
                int vi = __builtin_bit_cast(int, v);
                asm volatile("" : "+v"(vi));     // defeat load-sinking/remat
                w[i][jj] = __builtin_bit_cast(half2v, vi);
            }
        }

        if (tid < 128) {
            half2v hp = __builtin_amdgcn_cvt_pkrtz(h[b * H_ + 2 * tid],
                                                   h[b * H_ + 2 * tid + 1]);
            const int j = 2 * tid;
            ((half2v*)hbuf)[(j >> 5) * 20 + ((j & 31) >> 1)] = hp;
        }
        float xpn = xp_cur[(size_t)b * H_ + jf];
        __syncthreads();

        int p = 0;
        for (int s = 0; s < steps; s++) {
            const float xpc = xpn;
            if (s + 1 < steps)
                xpn = xp_cur[((size_t)(s + 1) * B_ + b) * H_ + jf];

            // this lane's 32-value h segment: 4 x ds_read_b128, conflict-free
            half2v hk[16];
            {
                const float4* hs = (const float4*)&hbuf[p * 160 + ks * 20];
                float4 t0 = hs[0], t1 = hs[1], t2 = hs[2], t3 = hs[3];
                *(float4*)&hk[0]  = t0;
                *(float4*)&hk[4]  = t1;
                *(float4*)&hk[8]  = t2;
                *(float4*)&hk[12] = t3;
            }

            float acc[8] = {0.f, 0.f, 0.f, 0.f, 0.f, 0.f, 0.f, 0.f};
            #pragma unroll
            for (int i = 0; i < 16; i++) {
                #pragma unroll
                for (int jj = 0; jj < 8; jj++)
                    acc[jj] = __builtin_amdgcn_fdot2(hk[i], w[i][jj],
                                                     acc[jj], false);
            }

            // split-butterfly reduce across the 8 ks lanes (lane bits 0..2);
            // each lane ends with ONE fully-reduced output (index jf).
            const bool b0 = (ks & 1), b1 = (ks & 2), b2 = (ks & 4);
            float r0, r1, r2, r3, q0, q1, v;
            {
                float s0 = b0 ? acc[0] : acc[4];
                float s1 = b0 ? acc[1] : acc[5];
                float s2 = b0 ? acc[2] : acc[6];
                float s3 = b0 ? acc[3] : acc[7];
                r0 = (b0 ? acc[4] : acc[0]) + __shfl_xor(s0, 1);
                r1 = (b0 ? acc[5] : acc[1]) + __shfl_xor(s1, 1);
                r2 = (b0 ? acc[6] : acc[2]) + __shfl_xor(s2, 1);
                r3 = (b0 ? acc[7] : acc[3]) + __shfl_xor(s3, 1);
            }
            {
                float s0 = b1 ? r0 : r2;
                float s1 = b1 ? r1 : r3;
                q0 = (b1 ? r2 : r0) + __shfl_xor(s0, 2);
                q1 = (b1 ? r3 : r1) + __shfl_xor(s1, 2);
            }
            {
                float s0 = b2 ? q0 : q1;
                v = (b2 ? q1 : q0) + __shfl_xor(s0, 4);
            }

            v += xpc;
            const float e2 = __expf(2.f * v);
            const float hn = 1.f - 2.f / (e2 + 1.f);   // tanh(v)
            ((__fp16*)hbuf)[((p ^ 1) * 160 + (jf >> 5) * 20) * 2 + (jf & 31)]
                = (__fp16)hn;
            if (s == steps - 1) h[b * H_ + jf] = hn;   // fp32 carry-out
            __syncthreads();
            p ^= 1;
        }
    } else if (A != nullptr) {
        // ---------------- gemm: xp_next = A @ Wih + bias (256 threads) -------
        float (*As)[68] = (float(*)[68])smem;
        float (*Bs)[64] = (float(*)[64])(smem + 32 * 68);

        const int gid = blockIdx.x - scan_blocks;
        const int bm = (gid >> 2) * 64;
        const int bn = (gid & 3) * 64;
        const int tx = tid & 15;
        const int ty = tid >> 4;

        float acc[4][4] = {};

        const int ar = tid >> 3;
        const int ak = (tid & 7) << 2;
        const int br = tid >> 4;
        const int bc = (tid & 15) << 2;

        for (int k0 = 0; k0 < E_; k0 += 32) {
            float4 a0 = *(const float4*)&A[(size_t)(bm + ar)      * E_ + k0 + ak];
            float4 a1 = *(const float4*)&A[(size_t)(bm + ar + 32) * E_ + k0 + ak];
            float4 bv0 = *(const float4*)&Wih[(size_t)(k0 + br)      * H_ + bn + bc];
            float4 bv1 = *(const float4*)&Wih[(size_t)(k0 + br + 16) * H_ + bn + bc];

            As[ak+0][ar]    = a0.x; As[ak+1][ar]    = a0.y; As[ak+2][ar]    = a0.z; As[ak+3][ar]    = a0.w;
            As[ak+0][ar+32] = a1.x; As[ak+1][ar+32] = a1.y; As[ak+2][ar+32] = a1.z; As[ak+3][ar+32] = a1.w;
            *(float4*)&Bs[br][bc]      = bv0;
            *(float4*)&Bs[br + 16][bc] = bv1;
            __syncthreads();

            #pragma unroll
            for (int kk = 0; kk < 32; kk++) {
                const float4 av = *(const float4*)&As[kk][ty << 2];
                const float4 bv = *(const float4*)&Bs[kk][tx << 2];
                acc[0][0] += av.x*bv.x; acc[0][1] += av.x*bv.y; acc[0][2] += av.x*bv.z; acc[0][3] += av.x*bv.w;
                acc[1][0] += av.y*bv.x; acc[1][1] += av.y*bv.y; acc[1][2] += av.y*bv.z; acc[1][3] += av.y*bv.w;
                acc[2][0] += av.z*bv.x; acc[2][1] += av.z*bv.y; acc[2][2] += av.z*bv.z; acc[2][3] += av.z*bv.w;
                acc[3][0] += av.w*bv.x; acc[3][1] += av.w*bv.y; acc[3][2] += av.w*bv.z; acc[3][3] += av.w*bv.w;
            }
            __syncthreads();
        }

        const float4 bb = *(const float4*)&bias[bn + (tx << 2)];
        #pragma unroll
        for (int i = 0; i < 4; i++) {
            float4 o;
            o.x = acc[i][0] + bb.x;
            o.y = acc[i][1] + bb.y;
            o.z = acc[i][2] + bb.z;
            o.w = acc[i][3] + bb.w;
            *(float4*)&xp_next[(size_t)(bm + (ty << 2) + i) * H_ + bn + (tx << 2)] = o;
        }
    }
}

extern "C" void kernel_launch(void* const* d_in, const int* in_sizes, int n_in,
                              void* d_out, int out_size, void* d_ws, size_t ws_size,
                              hipStream_t stream)
{
    const float* sentence = (const float*)d_in[0];  // [S,B,E]
    const float* h0       = (const float*)d_in[1];  // [B,H]
    const float* W_ih     = (const float*)d_in[2];  // [E,H]
    const float* W_hh     = (const float*)d_in[3];  // [H,H]
    const float* bias     = (const float*)d_in[4];  // [H]
    float* h  = (float*)d_out;
    float* ws = (float*)d_ws;

    // two ping-pong xp buffers, each [chunk*B, H]
    int chunk = 256;
    while ((size_t)2 * chunk * B_ * H_ * sizeof(float) > ws_size && chunk > 32)
        chunk >>= 1;
    const int nchunk = S_TOT / chunk;
    float* buf[2] = { ws, ws + (size_t)chunk * B_ * H_ };

    hipMemcpyAsync(h, h0, B_ * H_ * sizeof(float), hipMemcpyDeviceToDevice, stream);

    // pure gemm for chunk 0
    fused_step<<<chunk * 4, 256, 0, stream>>>(sentence, W_ih, bias, buf[0],
                                              nullptr, W_hh, h, 0, 0);
    for (int c = 0; c < nchunk; c++) {
        const bool last = (c == nchunk - 1);
        const int gemmb = last ? 0 : chunk * 4;
        const float* Anext = last ? nullptr
                                  : sentence + (size_t)(c + 1) * chunk * B_ * E_;
        fused_step<<<64 + gemmb, 256, 0, stream>>>(Anext, W_ih, bias,
                                                   buf[(c + 1) & 1],
                                                   buf[c & 1], W_hh, h,
                                                   chunk, 64);
    }
}